// Round 9
// baseline (988.079 us; speedup 1.0000x reference)
//
#include <hip/hip_runtime.h>

#define HID 2048
#define NE_ 32
#define EW_ 2944
#define ORIG_ 2880
#define TOPK_ 4
#define MAXNNZ_ 256
#define BS_ 1024
#define NEWTOT (NE_*EW_)
#define LDSP 40   // padded LDS row stride in halves (80B): 2-way banks = free

typedef unsigned short u16;
typedef _Float16 h8  __attribute__((ext_vector_type(8)));
typedef float  f32x4 __attribute__((ext_vector_type(4)));
typedef float  fv4   __attribute__((ext_vector_type(4)));
typedef short  s16x8 __attribute__((ext_vector_type(8)));

__device__ __forceinline__ u16 f2h_bits(float f){
  union{ _Float16 h; u16 u; } c; c.h = (_Float16)f; return c.u;
}
__device__ __forceinline__ float f16q(float f){ return (float)(_Float16)f; }

__device__ __forceinline__ h8 cvt8(fv4 a, fv4 b){
  h8 r;
  r[0]=(_Float16)a[0]; r[1]=(_Float16)a[1]; r[2]=(_Float16)a[2]; r[3]=(_Float16)a[3];
  r[4]=(_Float16)b[0]; r[5]=(_Float16)b[1]; r[6]=(_Float16)b[2]; r[7]=(_Float16)b[3];
  return r;
}
__device__ __forceinline__ int ldsx(int row, int q8){ return row*LDSP + q8*8; }

// ---------------- gating: f32 in, f16-quantized logits, top4 ----------------
__global__ __launch_bounds__(256) void k_gate(const float* __restrict__ x,
                                              const float* __restrict__ gw,
                                              float* __restrict__ rw,
                                              float* __restrict__ rwf,
                                              int* __restrict__ counts)
{
  __shared__ float slog[4][NE_];
  const int tid = threadIdx.x, wid = tid>>6, lane = tid&63;
  const int n = blockIdx.x*4 + wid;
  const float* xr = x + (size_t)n*HID + lane*32;
  float xf[32];
  #pragma unroll
  for (int i=0;i<8;i++){
    fv4 v = *(const fv4*)(xr + i*4);
    #pragma unroll
    for (int j=0;j<4;j++) xf[i*4+j] = v[j];
  }
  for (int e=0;e<NE_;e++){
    const float* gr = gw + (size_t)e*HID + lane*32;
    float p = 0.f;
    #pragma unroll
    for (int i=0;i<8;i++){
      fv4 v = *(const fv4*)(gr + i*4);
      #pragma unroll
      for (int j=0;j<4;j++) p += xf[i*4+j]*v[j];
    }
    #pragma unroll
    for (int s=32;s>0;s>>=1) p += __shfl_xor(p, s);
    if (lane==0) slog[wid][e] = f16q(p);   // reference rounds matmul to f16
  }
  if (lane==0){
    float mx=-1e30f;
    for (int e=0;e<NE_;e++) mx = fmaxf(mx, slog[wid][e]);
    float pr[NE_]; float sum=0.f;
    for (int e=0;e<NE_;e++){ float v=__expf(slog[wid][e]-mx); pr[e]=v; sum+=v; }
    for (int e=0;e<NE_;e++) pr[e] = pr[e]/sum;
    int   idx[TOPK_]; float val[TOPK_]; bool used[NE_];
    for (int e=0;e<NE_;e++) used[e]=false;
    float vs=0.f;
    for (int k=0;k<TOPK_;k++){
      float best=-1.f; int bi=0;
      for (int e=0;e<NE_;e++) if(!used[e] && pr[e]>best){best=pr[e];bi=e;}
      used[bi]=true; idx[k]=bi; val[k]=best; vs+=best;
    }
    float* rwr  = rw  + (size_t)n*NE_;
    float* rwfr = rwf + (size_t)n*NE_;
    for (int k=0;k<TOPK_;k++){
      float vraw = val[k]/vs;
      float q = f16q(vraw);            // reference: rw = sparse_rw.astype(f16)
      rwr[idx[k]]  = q;
      rwfr[idx[k]] = vraw;             // f32, for top-256 ranking (matches jax)
      if (q!=0.f) atomicAdd(counts+idx[k], 1);
    }
  }
}

// ---------------- rank experts by count (desc), tie -> lower index ----------
__global__ void k_rank(const int* __restrict__ counts, int* __restrict__ cdcs)
{
  if (threadIdx.x==0){
    int cnt[NE_]; bool used[NE_];
    for (int e=0;e<NE_;e++){ cnt[e]=counts[e]; used[e]=false; }
    for (int k=0;k<16;k++){
      int best=-1, bi=0;
      for (int e=0;e<NE_;e++) if(!used[e] && cnt[e]>best){best=cnt[e];bi=e;}
      used[bi]=true; cdcs[k]=bi;
    }
  }
}

// per-expert token lists, trimmed to nonzero weight (order-free, atomic slots)
//   dense  z<8 : tokens with rw!=0
//   sparse z>=8: tokens in exact top-256 of rwf (value desc, idx asc) AND rw!=0
__global__ __launch_bounds__(256) void k_lists(const float* __restrict__ rw,
                                               const float* __restrict__ rwf,
                                               const int* __restrict__ cdcs,
                                               int* __restrict__ tok_all,
                                               int* __restrict__ cnt_all)
{
  __shared__ float v[BS_];
  __shared__ int scnt;
  const int z = blockIdx.x;
  const int e = cdcs[z];
  const int tid = threadIdx.x;
  for (int i=tid;i<BS_;i+=256) tok_all[z*BS_+i] = 0;
  for (int i=tid;i<BS_;i+=256) v[i] = (z<8) ? rw[(size_t)i*NE_+e] : rwf[(size_t)i*NE_+e];
  if (tid==0) scnt = 0;
  __syncthreads();
  for (int i=tid;i<BS_;i+=256){
    bool take;
    if (z<8){
      take = (v[i]!=0.f);
    } else {
      float vi=v[i]; int r=0;
      for (int m=0;m<BS_;m++){
        float vm=v[m];
        r += (vm>vi) || (vm==vi && m<i);
      }
      take = (r<MAXNNZ_) && (rw[(size_t)i*NE_+e]!=0.f);
    }
    if (take){
      int slot = atomicAdd(&scnt,1);
      tok_all[z*BS_+slot] = i;
    }
  }
  __syncthreads();
  if (tid==0) cnt_all[z] = scnt;
}

// ------ fused up+gate gathered GEMM: 128 rows x 64 cols x {u,g}, 4 waves ----
__global__ __launch_bounds__(256) void k_fused(const float* __restrict__ x,
                                               const float* __restrict__ uw,
                                               const float* __restrict__ gww,
                                               const float* __restrict__ ub,
                                               const float* __restrict__ gb,
                                               const float* __restrict__ rw,
                                               const int* __restrict__ cdcs,
                                               const int* __restrict__ tok_all,
                                               const int* __restrict__ cnt_all,
                                               u16* __restrict__ act)
{
  const int z=blockIdx.z, bx=blockIdx.x, by=blockIdx.y;
  const int cnt = cnt_all[z];
  if (by*128 >= cnt) return;
  const int e = cdcs[z];
  __shared__ __align__(16) u16 ldsA[128*LDSP];
  __shared__ __align__(16) u16 ldsU[64*LDSP];
  __shared__ __align__(16) u16 ldsG[64*LDSP];
  const int tid=threadIdx.x, lane=tid&63, w=tid>>6;
  const int wr=w>>1, wc=w&1;
  const int srow=tid>>1, half=tid&1;
  const int token = tok_all[z*BS_ + by*128 + srow];
  const float* aptr = x + (size_t)token*HID + half*16;
  const int brow = (tid&127)>>1;
  const bool isU = tid < 128;
  const float* bptr = (isU ? uw : gww) + ((size_t)e*EW_ + bx*64 + brow)*HID + half*16;
  u16* ldsB = isU ? ldsU : ldsG;

  f32x4 au[4][2], ag[4][2];
  #pragma unroll
  for (int i=0;i<4;i++)
    #pragma unroll
    for (int j=0;j<2;j++)
      #pragma unroll
      for (int q=0;q<4;q++){ au[i][j][q]=0.f; ag[i][j][q]=0.f; }

  fv4 a0=*(const fv4*)aptr,     a1=*(const fv4*)(aptr+4),
      a2=*(const fv4*)(aptr+8), a3=*(const fv4*)(aptr+12);
  fv4 b0=*(const fv4*)bptr,     b1=*(const fv4*)(bptr+4),
      b2=*(const fv4*)(bptr+8), b3=*(const fv4*)(bptr+12);
  const int NK = HID/32;
  for (int kt=0; kt<NK; kt++){
    __syncthreads();
    *(h8*)&ldsA[ldsx(srow, half*2  )] = cvt8(a0,a1);
    *(h8*)&ldsA[ldsx(srow, half*2+1)] = cvt8(a2,a3);
    *(h8*)&ldsB[ldsx(brow, half*2  )] = cvt8(b0,b1);
    *(h8*)&ldsB[ldsx(brow, half*2+1)] = cvt8(b2,b3);
    __syncthreads();
    if (kt+1<NK){
      const int k1=(kt+1)*32;
      a0=*(const fv4*)(aptr+k1);   a1=*(const fv4*)(aptr+k1+4);
      a2=*(const fv4*)(aptr+k1+8); a3=*(const fv4*)(aptr+k1+12);
      b0=*(const fv4*)(bptr+k1);   b1=*(const fv4*)(bptr+k1+4);
      b2=*(const fv4*)(bptr+k1+8); b3=*(const fv4*)(bptr+k1+12);
    }
    const int kq = lane>>4;
    h8 af[4], fu[2], fg[2];
    #pragma unroll
    for (int m=0;m<4;m++) af[m] = *(const h8*)&ldsA[ldsx(wr*64+m*16+(lane&15), kq)];
    #pragma unroll
    for (int n2=0;n2<2;n2++){
      fu[n2] = *(const h8*)&ldsU[ldsx(wc*32+n2*16+(lane&15), kq)];
      fg[n2] = *(const h8*)&ldsG[ldsx(wc*32+n2*16+(lane&15), kq)];
    }
    #pragma unroll
    for (int m=0;m<4;m++)
      #pragma unroll
      for (int n2=0;n2<2;n2++){
        au[m][n2]=__builtin_amdgcn_mfma_f32_16x16x32_f16(af[m],fu[n2],au[m][n2],0,0,0);
        ag[m][n2]=__builtin_amdgcn_mfma_f32_16x16x32_f16(af[m],fg[n2],ag[m][n2],0,0,0);
      }
  }

  #pragma unroll
  for (int n2=0;n2<2;n2++){
    const int col = bx*64 + wc*32 + n2*16 + (lane&15);
    const float ubv = ub[(size_t)e*EW_ + col];
    const float gbv = gb[(size_t)e*EW_ + col];
    #pragma unroll
    for (int m=0;m<4;m++){
      #pragma unroll
      for (int j=0;j<4;j++){
        const int i = by*128 + wr*64 + m*16 + (lane>>4)*4 + j;
        float upv = f16q(au[m][n2][j] + ubv);
        float gtv = f16q(ag[m][n2][j] + gbv);
        float wv = 0.f;
        if (i < cnt) wv = rw[(size_t)tok_all[z*BS_+i]*NE_ + e];
        float gc = fminf(gtv, 7.0f);
        float uc = fminf(fmaxf(upv,-7.0f),7.0f);
        float glu = gc * (1.f/(1.f+__expf(-gc*1.702f)));
        act[((size_t)z*BS_+i)*EW_ + col] = f2h_bits((uc+1.f)*glu*wv);
      }
    }
  }
}

// -- gathered down GEMM (K trimmed to 2880, split x2): out += act · D^T ------
__global__ __launch_bounds__(256) void k_down(const u16* __restrict__ act,
                                              const float* __restrict__ dw,
                                              const int* __restrict__ cdcs,
                                              const int* __restrict__ tok_all,
                                              const int* __restrict__ cnt_all,
                                              float* __restrict__ outf)
{
  const int zz=blockIdx.z, bx=blockIdx.x, by=blockIdx.y;
  const int z = zz>>1, kh = zz&1;
  const int cnt = cnt_all[z];
  if (by*128 >= cnt) return;
  const int e = cdcs[z];
  __shared__ __align__(16) u16 ldsA[128*LDSP];
  __shared__ __align__(16) u16 ldsB[128*LDSP];
  const int tid=threadIdx.x, lane=tid&63, wid=tid>>6;
  const int srow=tid>>1, half=tid&1;
  const int kbase = kh*1440;

  const u16* aptr = act + ((size_t)z*BS_ + by*128 + srow)*EW_ + kbase + half*16;
  const float* bptr = dw + (size_t)(bx*128 + srow)*NEWTOT + (size_t)e*EW_ + kbase + half*16;

  f32x4 acc[4][4];
  #pragma unroll
  for (int i=0;i<4;i++)
    #pragma unroll
    for (int j=0;j<4;j++)
      #pragma unroll
      for (int q=0;q<4;q++) acc[i][j][q]=0.f;

  const int wr=wid>>1, wc=wid&1;
  s16x8 ra0 = *(const s16x8*)aptr;
  s16x8 ra1 = *(const s16x8*)(aptr+8);
  fv4 b0=*(const fv4*)bptr,     b1=*(const fv4*)(bptr+4),
      b2=*(const fv4*)(bptr+8), b3=*(const fv4*)(bptr+12);
  const int NK = 1440/32;  // 45
  for (int kt=0; kt<NK; kt++){
    __syncthreads();
    *(s16x8*)&ldsA[ldsx(srow, half*2  )] = ra0;
    *(s16x8*)&ldsA[ldsx(srow, half*2+1)] = ra1;
    *(h8*)&ldsB[ldsx(srow, half*2  )] = cvt8(b0,b1);
    *(h8*)&ldsB[ldsx(srow, half*2+1)] = cvt8(b2,b3);
    __syncthreads();
    if (kt+1<NK){
      const int k1 = (kt+1)*32;
      ra0 = *(const s16x8*)(aptr + k1);
      ra1 = *(const s16x8*)(aptr + k1 + 8);
      b0=*(const fv4*)(bptr+k1);   b1=*(const fv4*)(bptr+k1+4);
      b2=*(const fv4*)(bptr+k1+8); b3=*(const fv4*)(bptr+k1+12);
    }
    h8 af[4], bfr[4];
    const int kq = lane>>4;
    #pragma unroll
    for (int m=0;m<4;m++)    af[m]  = *(const h8*)&ldsA[ldsx(wr*64+m*16+(lane&15), kq)];
    #pragma unroll
    for (int n2=0;n2<4;n2++) bfr[n2] = *(const h8*)&ldsB[ldsx(wc*64+n2*16+(lane&15), kq)];
    #pragma unroll
    for (int m=0;m<4;m++)
      #pragma unroll
      for (int n2=0;n2<4;n2++)
        acc[m][n2]=__builtin_amdgcn_mfma_f32_16x16x32_f16(af[m],bfr[n2],acc[m][n2],0,0,0);
  }

  #pragma unroll
  for (int m=0;m<4;m++){
    #pragma unroll
    for (int j=0;j<4;j++){
      const int il = wr*64 + m*16 + (lane>>4)*4 + j;
      const int orow = tok_all[z*BS_ + by*128 + il];
      #pragma unroll
      for (int n2=0;n2<4;n2++){
        const int col = bx*128 + wc*64 + n2*16 + (lane&15);
        atomicAdd(outf + (size_t)orow*HID + col, acc[m][n2][j]);
      }
    }
  }
}

extern "C" void kernel_launch(void* const* d_in, const int* in_sizes, int n_in,
                              void* d_out, int out_size, void* d_ws, size_t ws_size,
                              hipStream_t stream)
{
  const float* x  = (const float*)d_in[0];
  const float* gw = (const float*)d_in[1];
  const float* u  = (const float*)d_in[2];
  const float* g  = (const float*)d_in[3];
  const float* dw = (const float*)d_in[4];
  const float* ub = (const float*)d_in[5];
  const float* gb = (const float*)d_in[6];

  char* ws = (char*)d_ws;
  size_t off = 0;
  auto alloc = [&](size_t bytes)->void*{ void* p = ws + off; off += (bytes + 255) & ~(size_t)255; return p; };
  float* rw     = (float*)alloc((size_t)BS_*NE_*4);
  float* rwf    = (float*)alloc((size_t)BS_*NE_*4);
  int*   counts = (int*)  alloc(NE_*4);
  size_t zero_span = off;                 // rw + rwf + counts must start zeroed
  int*   cdcs   = (int*)  alloc(16*4);
  int*   tok_all= (int*)  alloc((size_t)16*BS_*4);
  int*   cnt_all= (int*)  alloc(16*4);
  u16*   act    = (u16*)  alloc((size_t)16*BS_*EW_*2);
  if (off > ws_size) return;

  hipMemsetAsync(ws, 0, zero_span, stream);
  hipMemsetAsync(d_out, 0, (size_t)BS_*HID*4, stream);   // f32 output accumulator

  k_gate <<<BS_/4, 256, 0, stream>>>(x, gw, rw, rwf, counts);
  k_rank <<<1,     64,  0, stream>>>(counts, cdcs);
  k_lists<<<16,    256, 0, stream>>>(rw, rwf, cdcs, tok_all, cnt_all);

  k_fused<<<dim3(ORIG_/64, 8, 16), 256, 0, stream>>>(x, u, g, ub, gb, rw,
                                                     cdcs, tok_all, cnt_all, act);
  k_down <<<dim3(HID/128, 8, 32), 256, 0, stream>>>(act, dw, cdcs, tok_all,
                                                    cnt_all, (float*)d_out);
}

// Round 10
// 807.538 us; speedup vs baseline: 1.2236x; 1.2236x over previous
//
#include <hip/hip_runtime.h>

#define HID 2048
#define NE_ 32
#define EW_ 2944
#define ORIG_ 2880
#define TOPK_ 4
#define MAXNNZ_ 256
#define BS_ 1024
#define NEWTOT (NE_*EW_)
#define LDSP 40   // padded LDS row stride in halves (80B)

typedef unsigned short u16;
typedef _Float16 h8  __attribute__((ext_vector_type(8)));
typedef float  f32x4 __attribute__((ext_vector_type(4)));
typedef float  fv4   __attribute__((ext_vector_type(4)));
typedef short  s16x8 __attribute__((ext_vector_type(8)));

__device__ __forceinline__ u16 f2h_bits(float f){
  union{ _Float16 h; u16 u; } c; c.h = (_Float16)f; return c.u;
}
__device__ __forceinline__ float f16q(float f){ return (float)(_Float16)f; }

__device__ __forceinline__ h8 cvt8(fv4 a, fv4 b){
  h8 r;
  r[0]=(_Float16)a[0]; r[1]=(_Float16)a[1]; r[2]=(_Float16)a[2]; r[3]=(_Float16)a[3];
  r[4]=(_Float16)b[0]; r[5]=(_Float16)b[1]; r[6]=(_Float16)b[2]; r[7]=(_Float16)b[3];
  return r;
}
__device__ __forceinline__ int ldsx(int row, int q8){ return row*LDSP + q8*8; }

// ---------------- gating: f32 in, f16-quantized logits, top4 ----------------
__global__ __launch_bounds__(256) void k_gate(const float* __restrict__ x,
                                              const float* __restrict__ gw,
                                              float* __restrict__ rw,
                                              float* __restrict__ rwf,
                                              int* __restrict__ counts)
{
  __shared__ float slog[4][NE_];
  const int tid = threadIdx.x, wid = tid>>6, lane = tid&63;
  const int n = blockIdx.x*4 + wid;
  const float* xr = x + (size_t)n*HID + lane*32;
  float xf[32];
  #pragma unroll
  for (int i=0;i<8;i++){
    fv4 v = *(const fv4*)(xr + i*4);
    #pragma unroll
    for (int j=0;j<4;j++) xf[i*4+j] = v[j];
  }
  for (int e=0;e<NE_;e++){
    const float* gr = gw + (size_t)e*HID + lane*32;
    float p = 0.f;
    #pragma unroll
    for (int i=0;i<8;i++){
      fv4 v = *(const fv4*)(gr + i*4);
      #pragma unroll
      for (int j=0;j<4;j++) p += xf[i*4+j]*v[j];
    }
    #pragma unroll
    for (int s=32;s>0;s>>=1) p += __shfl_xor(p, s);
    if (lane==0) slog[wid][e] = f16q(p);
  }
  if (lane==0){
    float mx=-1e30f;
    for (int e=0;e<NE_;e++) mx = fmaxf(mx, slog[wid][e]);
    float pr[NE_]; float sum=0.f;
    for (int e=0;e<NE_;e++){ float v=__expf(slog[wid][e]-mx); pr[e]=v; sum+=v; }
    for (int e=0;e<NE_;e++) pr[e] = pr[e]/sum;
    int   idx[TOPK_]; float val[TOPK_]; bool used[NE_];
    for (int e=0;e<NE_;e++) used[e]=false;
    float vs=0.f;
    for (int k=0;k<TOPK_;k++){
      float best=-1.f; int bi=0;
      for (int e=0;e<NE_;e++) if(!used[e] && pr[e]>best){best=pr[e];bi=e;}
      used[bi]=true; idx[k]=bi; val[k]=best; vs+=best;
    }
    float* rwr  = rw  + (size_t)n*NE_;
    float* rwfr = rwf + (size_t)n*NE_;
    for (int k=0;k<TOPK_;k++){
      float vraw = val[k]/vs;
      float q = f16q(vraw);
      rwr[idx[k]]  = q;
      rwfr[idx[k]] = vraw;
      if (q!=0.f) atomicAdd(counts+idx[k], 1);
    }
  }
}

// ---------------- rank experts by count (desc), tie -> lower index ----------
__global__ void k_rank(const int* __restrict__ counts, int* __restrict__ cdcs)
{
  if (threadIdx.x==0){
    int cnt[NE_]; bool used[NE_];
    for (int e=0;e<NE_;e++){ cnt[e]=counts[e]; used[e]=false; }
    for (int k=0;k<16;k++){
      int best=-1, bi=0;
      for (int e=0;e<NE_;e++) if(!used[e] && cnt[e]>best){best=cnt[e];bi=e;}
      used[bi]=true; cdcs[k]=bi;
    }
  }
}

// per-expert token lists (trimmed to rw!=0) + inverse map token->(z,slot) ----
__global__ __launch_bounds__(256) void k_lists(const float* __restrict__ rw,
                                               const float* __restrict__ rwf,
                                               const int* __restrict__ cdcs,
                                               int* __restrict__ tok_all,
                                               int* __restrict__ cnt_all,
                                               int* __restrict__ inv,
                                               int* __restrict__ invcnt)
{
  __shared__ float v[BS_];
  __shared__ int scnt;
  const int z = blockIdx.x;
  const int e = cdcs[z];
  const int tid = threadIdx.x;
  for (int i=tid;i<BS_;i+=256) tok_all[z*BS_+i] = 0;
  for (int i=tid;i<BS_;i+=256) v[i] = (z<8) ? rw[(size_t)i*NE_+e] : rwf[(size_t)i*NE_+e];
  if (tid==0) scnt = 0;
  __syncthreads();
  for (int i=tid;i<BS_;i+=256){
    bool take;
    if (z<8){
      take = (v[i]!=0.f);
    } else {
      float vi=v[i]; int r=0;
      for (int m=0;m<BS_;m++){
        float vm=v[m];
        r += (vm>vi) || (vm==vi && m<i);
      }
      take = (r<MAXNNZ_) && (rw[(size_t)i*NE_+e]!=0.f);
    }
    if (take){
      int slot = atomicAdd(&scnt,1);
      tok_all[z*BS_+slot] = i;
      int c = atomicAdd(&invcnt[i],1);
      inv[i*4+c] = (z<<16) | slot;
    }
  }
  __syncthreads();
  if (tid==0) cnt_all[z] = scnt;
}

// ------ fused up+gate gathered GEMM: 256 rows x 64 cols x {u,g}, 8 waves ----
__global__ __launch_bounds__(512) void k_fused(const float* __restrict__ x,
                                               const float* __restrict__ uw,
                                               const float* __restrict__ gww,
                                               const float* __restrict__ ub,
                                               const float* __restrict__ gb,
                                               const float* __restrict__ rw,
                                               const int* __restrict__ cdcs,
                                               const int* __restrict__ tok_all,
                                               const int* __restrict__ cnt_all,
                                               u16* __restrict__ act)
{
  const int z=blockIdx.z, bx=blockIdx.x, by=blockIdx.y;
  const int cnt = cnt_all[z];
  if (by*256 >= cnt) return;
  const int e = cdcs[z];
  __shared__ __align__(16) u16 ldsA[256*LDSP];
  __shared__ __align__(16) u16 ldsU[64*LDSP];
  __shared__ __align__(16) u16 ldsG[64*LDSP];
  const int tid=threadIdx.x, lane=tid&63, w=tid>>6;
  const int wr=w>>1, wc=w&1;
  const int srow=tid>>1, half=tid&1;
  const int token = tok_all[z*BS_ + by*256 + srow];
  const float* aptr = x + (size_t)token*HID + half*16;
  const bool doB = tid < 256;
  const int mat = tid>>7;            // 0=U, 1=G (valid when doB)
  const int br  = (tid&127)>>1;
  const float* bptr = (mat ? gww : uw) + ((size_t)e*EW_ + bx*64 + br)*HID + half*16;
  u16* ldsBp = mat ? ldsG : ldsU;

  f32x4 au[4][2], ag[4][2];
  #pragma unroll
  for (int i=0;i<4;i++)
    #pragma unroll
    for (int j=0;j<2;j++)
      #pragma unroll
      for (int q=0;q<4;q++){ au[i][j][q]=0.f; ag[i][j][q]=0.f; }

  fv4 a0=*(const fv4*)aptr,     a1=*(const fv4*)(aptr+4),
      a2=*(const fv4*)(aptr+8), a3=*(const fv4*)(aptr+12);
  fv4 b0,b1,b2,b3;
  if (doB){
    b0=*(const fv4*)bptr;     b1=*(const fv4*)(bptr+4);
    b2=*(const fv4*)(bptr+8); b3=*(const fv4*)(bptr+12);
  }
  const int NK = HID/32;
  for (int kt=0; kt<NK; kt++){
    __syncthreads();
    *(h8*)&ldsA[ldsx(srow, half*2  )] = cvt8(a0,a1);
    *(h8*)&ldsA[ldsx(srow, half*2+1)] = cvt8(a2,a3);
    if (doB){
      *(h8*)&ldsBp[ldsx(br, half*2  )] = cvt8(b0,b1);
      *(h8*)&ldsBp[ldsx(br, half*2+1)] = cvt8(b2,b3);
    }
    __syncthreads();
    if (kt+1<NK){
      const int k1=(kt+1)*32;
      a0=*(const fv4*)(aptr+k1);   a1=*(const fv4*)(aptr+k1+4);
      a2=*(const fv4*)(aptr+k1+8); a3=*(const fv4*)(aptr+k1+12);
      if (doB){
        b0=*(const fv4*)(bptr+k1);   b1=*(const fv4*)(bptr+k1+4);
        b2=*(const fv4*)(bptr+k1+8); b3=*(const fv4*)(bptr+k1+12);
      }
    }
    const int kq = lane>>4;
    h8 af[4], fu[2], fg[2];
    #pragma unroll
    for (int m=0;m<4;m++) af[m] = *(const h8*)&ldsA[ldsx(wr*64+m*16+(lane&15), kq)];
    #pragma unroll
    for (int n2=0;n2<2;n2++){
      fu[n2] = *(const h8*)&ldsU[ldsx(wc*32+n2*16+(lane&15), kq)];
      fg[n2] = *(const h8*)&ldsG[ldsx(wc*32+n2*16+(lane&15), kq)];
    }
    #pragma unroll
    for (int m=0;m<4;m++)
      #pragma unroll
      for (int n2=0;n2<2;n2++){
        au[m][n2]=__builtin_amdgcn_mfma_f32_16x16x32_f16(af[m],fu[n2],au[m][n2],0,0,0);
        ag[m][n2]=__builtin_amdgcn_mfma_f32_16x16x32_f16(af[m],fg[n2],ag[m][n2],0,0,0);
      }
  }

  #pragma unroll
  for (int n2=0;n2<2;n2++){
    const int col = bx*64 + wc*32 + n2*16 + (lane&15);
    const float ubv = ub[(size_t)e*EW_ + col];
    const float gbv = gb[(size_t)e*EW_ + col];
    #pragma unroll
    for (int m=0;m<4;m++){
      #pragma unroll
      for (int j=0;j<4;j++){
        const int s = by*256 + wr*64 + m*16 + (lane>>4)*4 + j;
        float upv = f16q(au[m][n2][j] + ubv);
        float gtv = f16q(ag[m][n2][j] + gbv);
        float wv = 0.f;
        if (s < cnt) wv = rw[(size_t)tok_all[z*BS_+s]*NE_ + e];
        float gc = fminf(gtv, 7.0f);
        float uc = fminf(fmaxf(upv,-7.0f),7.0f);
        float glu = gc * (1.f/(1.f+__expf(-gc*1.702f)));
        act[((size_t)z*BS_+s)*ORIG_ + col] = f2h_bits((uc+1.f)*glu*wv);
      }
    }
  }
}

// -- gathered down GEMM: contrib[zz][slot][h] = act·D^T, no atomics ----------
// tile 256 rows x 128 cols, K=1440 per kh-half, 8 waves (4 row x 2 col)
__global__ __launch_bounds__(512) void k_down(const u16* __restrict__ act,
                                              const float* __restrict__ dw,
                                              const int* __restrict__ cdcs,
                                              const int* __restrict__ cnt_all,
                                              float* __restrict__ contrib)
{
  const int zz=blockIdx.z, bx=blockIdx.x, by=blockIdx.y;
  const int z = zz>>1, kh = zz&1;
  const int cnt = cnt_all[z];
  if (by*256 >= cnt) return;
  const int e = cdcs[z];
  __shared__ __align__(16) u16 ldsA[256*LDSP];
  __shared__ __align__(16) u16 ldsB[128*LDSP];
  const int tid=threadIdx.x, lane=tid&63, w=tid>>6;
  const int wr=w>>1, wc=w&1;
  const int srowA=tid>>1, halfA=tid&1;
  const int srowB=tid>>2, q4=tid&3;
  const int kbase = kh*1440;

  const u16* aptr = act + ((size_t)z*BS_ + by*256 + srowA)*ORIG_ + kbase + halfA*16;
  const float* bptr = dw + (size_t)(bx*128 + srowB)*NEWTOT + (size_t)e*EW_ + kbase + q4*8;

  f32x4 acc[4][4];
  #pragma unroll
  for (int i=0;i<4;i++)
    #pragma unroll
    for (int j=0;j<4;j++)
      #pragma unroll
      for (int q=0;q<4;q++) acc[i][j][q]=0.f;

  s16x8 ra0 = *(const s16x8*)aptr;
  s16x8 ra1 = *(const s16x8*)(aptr+8);
  fv4 b0=*(const fv4*)bptr, b1=*(const fv4*)(bptr+4);
  const int NK = 1440/32;  // 45
  for (int kt=0; kt<NK; kt++){
    __syncthreads();
    *(s16x8*)&ldsA[ldsx(srowA, halfA*2  )] = ra0;
    *(s16x8*)&ldsA[ldsx(srowA, halfA*2+1)] = ra1;
    *(h8*)&ldsB[ldsx(srowB, q4)] = cvt8(b0,b1);
    __syncthreads();
    if (kt+1<NK){
      const int k1 = (kt+1)*32;
      ra0 = *(const s16x8*)(aptr + k1);
      ra1 = *(const s16x8*)(aptr + k1 + 8);
      b0=*(const fv4*)(bptr+k1); b1=*(const fv4*)(bptr+k1+4);
    }
    h8 af[4], bfr[4];
    const int kq = lane>>4;
    #pragma unroll
    for (int m=0;m<4;m++)    af[m]  = *(const h8*)&ldsA[ldsx(wr*64+m*16+(lane&15), kq)];
    #pragma unroll
    for (int n2=0;n2<4;n2++) bfr[n2] = *(const h8*)&ldsB[ldsx(wc*64+n2*16+(lane&15), kq)];
    #pragma unroll
    for (int m=0;m<4;m++)
      #pragma unroll
      for (int n2=0;n2<4;n2++)
        acc[m][n2]=__builtin_amdgcn_mfma_f32_16x16x32_f16(af[m],bfr[n2],acc[m][n2],0,0,0);
  }

  #pragma unroll
  for (int m=0;m<4;m++){
    #pragma unroll
    for (int j=0;j<4;j++){
      const int slot = by*256 + wr*64 + m*16 + (lane>>4)*4 + j;
      #pragma unroll
      for (int n2=0;n2<4;n2++){
        const int col = bx*128 + wc*64 + n2*16 + (lane&15);
        contrib[((size_t)zz*BS_ + slot)*HID + col] = acc[m][n2][j];
      }
    }
  }
}

// ---- combine: out[n][h] = sum over token n's <=4 lists (both kh planes) ----
__global__ __launch_bounds__(256) void k_combine(const float* __restrict__ contrib,
                                                 const int* __restrict__ inv,
                                                 const int* __restrict__ invcnt,
                                                 float* __restrict__ out)
{
  const int gid = blockIdx.x*256 + threadIdx.x;
  const int base = gid*4;
  const int n = base >> 11;
  const int h = base & 2047;
  fv4 acc = {0.f,0.f,0.f,0.f};
  const int c = invcnt[n];
  for (int j=0;j<c;j++){
    const int code = inv[n*4+j];
    const int z = code>>16;
    const int slot = code & 0xFFFF;
    const float* p = contrib + ((size_t)(z*2)*BS_ + slot)*HID + h;
    acc += *(const fv4*)p;
    acc += *(const fv4*)(p + (size_t)BS_*HID);
  }
  *(fv4*)(out + base) = acc;
}

extern "C" void kernel_launch(void* const* d_in, const int* in_sizes, int n_in,
                              void* d_out, int out_size, void* d_ws, size_t ws_size,
                              hipStream_t stream)
{
  const float* x  = (const float*)d_in[0];
  const float* gw = (const float*)d_in[1];
  const float* u  = (const float*)d_in[2];
  const float* g  = (const float*)d_in[3];
  const float* dw = (const float*)d_in[4];
  const float* ub = (const float*)d_in[5];
  const float* gb = (const float*)d_in[6];

  char* ws = (char*)d_ws;
  size_t off = 0;
  auto alloc = [&](size_t bytes)->void*{ void* p = ws + off; off += (bytes + 255) & ~(size_t)255; return p; };
  float* rw     = (float*)alloc((size_t)BS_*NE_*4);
  float* rwf    = (float*)alloc((size_t)BS_*NE_*4);
  int*   counts = (int*)  alloc(NE_*4);
  int*   invcnt = (int*)  alloc(BS_*4);
  size_t zero_span = off;             // rw+rwf+counts+invcnt must start zeroed
  int*   cdcs   = (int*)  alloc(16*4);
  int*   cnt_all= (int*)  alloc(16*4);
  int*   tok_all= (int*)  alloc((size_t)16*BS_*4);
  int*   inv    = (int*)  alloc((size_t)BS_*4*4);
  u16*   act    = (u16*)  alloc((size_t)16*BS_*ORIG_*2);
  float* contrib= (float*)alloc((size_t)32*BS_*HID*4);
  if (off > ws_size) return;

  hipMemsetAsync(ws, 0, zero_span, stream);

  k_gate <<<BS_/4, 256, 0, stream>>>(x, gw, rw, rwf, counts);
  k_rank <<<1,     64,  0, stream>>>(counts, cdcs);
  k_lists<<<16,    256, 0, stream>>>(rw, rwf, cdcs, tok_all, cnt_all, inv, invcnt);

  k_fused<<<dim3(ORIG_/64, 4, 16), 512, 0, stream>>>(x, u, g, ub, gb, rw,
                                                     cdcs, tok_all, cnt_all, act);
  k_down <<<dim3(HID/128, 4, 32), 512, 0, stream>>>(act, dw, cdcs, cnt_all, contrib);
  k_combine<<<(BS_*HID/4)/256, 256, 0, stream>>>(contrib, inv, invcnt, (float*)d_out);
}

// Round 11
// 642.444 us; speedup vs baseline: 1.5380x; 1.2570x over previous
//
#include <hip/hip_runtime.h>

#define HID 2048
#define NE_ 32
#define EW_ 2944
#define ORIG_ 2880
#define TOPK_ 4
#define MAXNNZ_ 256
#define BS_ 1024
#define NEWTOT (NE_*EW_)
#define LDSP 40   // padded LDS row stride in halves (80B): 2-way b128 banks

typedef unsigned short u16;
typedef _Float16 h8  __attribute__((ext_vector_type(8)));
typedef float  f32x4 __attribute__((ext_vector_type(4)));
typedef float  fv4   __attribute__((ext_vector_type(4)));
typedef short  s16x8 __attribute__((ext_vector_type(8)));

__device__ __forceinline__ u16 f2h_bits(float f){
  union{ _Float16 h; u16 u; } c; c.h = (_Float16)f; return c.u;
}
__device__ __forceinline__ float f16q(float f){ return (float)(_Float16)f; }

__device__ __forceinline__ h8 cvt8(fv4 a, fv4 b){
  h8 r;
  r[0]=(_Float16)a[0]; r[1]=(_Float16)a[1]; r[2]=(_Float16)a[2]; r[3]=(_Float16)a[3];
  r[4]=(_Float16)b[0]; r[5]=(_Float16)b[1]; r[6]=(_Float16)b[2]; r[7]=(_Float16)b[3];
  return r;
}
__device__ __forceinline__ int ldsx(int row, int q8){ return row*LDSP + q8*8; }

// ---------------- gating: f32 in, f16-quantized logits, top4 ----------------
__global__ __launch_bounds__(256) void k_gate(const float* __restrict__ x,
                                              const float* __restrict__ gw,
                                              float* __restrict__ rw,
                                              float* __restrict__ rwf,
                                              int* __restrict__ counts)
{
  __shared__ float slog[4][NE_];
  const int tid = threadIdx.x, wid = tid>>6, lane = tid&63;
  const int n = blockIdx.x*4 + wid;
  const float* xr = x + (size_t)n*HID + lane*32;
  float xf[32];
  #pragma unroll
  for (int i=0;i<8;i++){
    fv4 v = *(const fv4*)(xr + i*4);
    #pragma unroll
    for (int j=0;j<4;j++) xf[i*4+j] = v[j];
  }
  for (int e=0;e<NE_;e++){
    const float* gr = gw + (size_t)e*HID + lane*32;
    float p = 0.f;
    #pragma unroll
    for (int i=0;i<8;i++){
      fv4 v = *(const fv4*)(gr + i*4);
      #pragma unroll
      for (int j=0;j<4;j++) p += xf[i*4+j]*v[j];
    }
    #pragma unroll
    for (int s=32;s>0;s>>=1) p += __shfl_xor(p, s);
    if (lane==0) slog[wid][e] = f16q(p);
  }
  if (lane==0){
    float mx=-1e30f;
    for (int e=0;e<NE_;e++) mx = fmaxf(mx, slog[wid][e]);
    float pr[NE_]; float sum=0.f;
    for (int e=0;e<NE_;e++){ float v=__expf(slog[wid][e]-mx); pr[e]=v; sum+=v; }
    for (int e=0;e<NE_;e++) pr[e] = pr[e]/sum;
    int   idx[TOPK_]; float val[TOPK_]; bool used[NE_];
    for (int e=0;e<NE_;e++) used[e]=false;
    float vs=0.f;
    for (int k=0;k<TOPK_;k++){
      float best=-1.f; int bi=0;
      for (int e=0;e<NE_;e++) if(!used[e] && pr[e]>best){best=pr[e];bi=e;}
      used[bi]=true; idx[k]=bi; val[k]=best; vs+=best;
    }
    float* rwr  = rw  + (size_t)n*NE_;
    float* rwfr = rwf + (size_t)n*NE_;
    for (int k=0;k<TOPK_;k++){
      float vraw = val[k]/vs;
      float q = f16q(vraw);
      rwr[idx[k]]  = q;
      rwfr[idx[k]] = vraw;
      if (q!=0.f) atomicAdd(counts+idx[k], 1);
    }
  }
}

// ---------------- rank experts by count (desc), tie -> lower index ----------
__global__ void k_rank(const int* __restrict__ counts, int* __restrict__ cdcs)
{
  if (threadIdx.x==0){
    int cnt[NE_]; bool used[NE_];
    for (int e=0;e<NE_;e++){ cnt[e]=counts[e]; used[e]=false; }
    for (int k=0;k<16;k++){
      int best=-1, bi=0;
      for (int e=0;e<NE_;e++) if(!used[e] && cnt[e]>best){best=cnt[e];bi=e;}
      used[bi]=true; cdcs[k]=bi;
    }
  }
}

// per-expert token lists (trimmed to rw!=0) + inverse map token->(z,slot) ----
__global__ __launch_bounds__(256) void k_lists(const float* __restrict__ rw,
                                               const float* __restrict__ rwf,
                                               const int* __restrict__ cdcs,
                                               int* __restrict__ tok_all,
                                               int* __restrict__ cnt_all,
                                               int* __restrict__ inv,
                                               int* __restrict__ invcnt)
{
  __shared__ float v[BS_];
  __shared__ int scnt;
  const int z = blockIdx.x;
  const int e = cdcs[z];
  const int tid = threadIdx.x;
  for (int i=tid;i<BS_;i+=256) tok_all[z*BS_+i] = 0;
  for (int i=tid;i<BS_;i+=256) v[i] = (z<8) ? rw[(size_t)i*NE_+e] : rwf[(size_t)i*NE_+e];
  if (tid==0) scnt = 0;
  __syncthreads();
  for (int i=tid;i<BS_;i+=256){
    bool take;
    if (z<8){
      take = (v[i]!=0.f);
    } else {
      float vi=v[i]; int r=0;
      for (int m=0;m<BS_;m++){
        float vm=v[m];
        r += (vm>vi) || (vm==vi && m<i);
      }
      take = (r<MAXNNZ_) && (rw[(size_t)i*NE_+e]!=0.f);
    }
    if (take){
      int slot = atomicAdd(&scnt,1);
      tok_all[z*BS_+slot] = i;
      int c = atomicAdd(&invcnt[i],1);
      inv[i*4+c] = (z<<16) | slot;
    }
  }
  __syncthreads();
  if (tid==0) cnt_all[z] = scnt;
}

// ------ fused up+gate gathered GEMM: 128 rows x 64 cols x {u,g} -------------
// 256 thr / 4 waves; dbuf LDS; ONE barrier per k-step; lean staging regs.
__global__ __launch_bounds__(256) void k_fused(const float* __restrict__ x,
                                               const float* __restrict__ uw,
                                               const float* __restrict__ gww,
                                               const float* __restrict__ ub,
                                               const float* __restrict__ gb,
                                               const float* __restrict__ rw,
                                               const int* __restrict__ cdcs,
                                               const int* __restrict__ tok_all,
                                               const int* __restrict__ cnt_all,
                                               u16* __restrict__ act)
{
  const int z=blockIdx.z, bx=blockIdx.x, by=blockIdx.y;
  const int cnt = cnt_all[z];
  if (by*128 >= cnt) return;
  const int e = cdcs[z];
  __shared__ __align__(16) u16 ldsA[2][128*LDSP];
  __shared__ __align__(16) u16 ldsB[2][128*LDSP];  // rows 0-63 = U, 64-127 = G
  const int tid=threadIdx.x, lane=tid&63, w=tid>>6;
  const int wr=w>>1, wc=w&1;

  // staging: 2 slots per thread for A (rows r, r+64), 2 for B (U-row, G-row)
  const int ar = tid>>2, ach = tid&3;
  const int tokA0 = tok_all[z*BS_ + by*128 + ar];
  const int tokA1 = tok_all[z*BS_ + by*128 + ar + 64];
  const float* ap0 = x + (size_t)tokA0*HID + ach*8;
  const float* ap1 = x + (size_t)tokA1*HID + ach*8;
  const float* bp0 = uw  + ((size_t)e*EW_ + bx*64 + ar)*HID + ach*8;
  const float* bp1 = gww + ((size_t)e*EW_ + bx*64 + ar)*HID + ach*8;

  f32x4 au[4][2], ag[4][2];
  #pragma unroll
  for (int i=0;i<4;i++)
    #pragma unroll
    for (int j=0;j<2;j++)
      #pragma unroll
      for (int q=0;q<4;q++){ au[i][j][q]=0.f; ag[i][j][q]=0.f; }

  fv4 aR00=*(const fv4*)ap0, aR01=*(const fv4*)(ap0+4);
  fv4 aR10=*(const fv4*)ap1, aR11=*(const fv4*)(ap1+4);
  fv4 bR00=*(const fv4*)bp0, bR01=*(const fv4*)(bp0+4);
  fv4 bR10=*(const fv4*)bp1, bR11=*(const fv4*)(bp1+4);
  const int NK = HID/32;  // 64
  for (int kt=0; kt<NK; kt++){
    u16* A = ldsA[kt&1]; u16* B = ldsB[kt&1];
    *(h8*)&A[ldsx(ar,    ach)] = cvt8(aR00,aR01);
    *(h8*)&A[ldsx(ar+64, ach)] = cvt8(aR10,aR11);
    *(h8*)&B[ldsx(ar,    ach)] = cvt8(bR00,bR01);
    *(h8*)&B[ldsx(ar+64, ach)] = cvt8(bR10,bR11);
    if (kt+1<NK){
      const int k1=(kt+1)*32;
      aR00=*(const fv4*)(ap0+k1); aR01=*(const fv4*)(ap0+k1+4);
      aR10=*(const fv4*)(ap1+k1); aR11=*(const fv4*)(ap1+k1+4);
      bR00=*(const fv4*)(bp0+k1); bR01=*(const fv4*)(bp0+k1+4);
      bR10=*(const fv4*)(bp1+k1); bR11=*(const fv4*)(bp1+k1+4);
    }
    __syncthreads();
    const int kq = lane>>4;
    const u16* Ar = ldsA[kt&1]; const u16* Br = ldsB[kt&1];
    h8 af[4], fu[2], fg[2];
    #pragma unroll
    for (int m=0;m<4;m++) af[m] = *(const h8*)&Ar[ldsx(wr*64+m*16+(lane&15), kq)];
    #pragma unroll
    for (int n2=0;n2<2;n2++){
      fu[n2] = *(const h8*)&Br[ldsx(wc*32+n2*16+(lane&15), kq)];
      fg[n2] = *(const h8*)&Br[ldsx(64+wc*32+n2*16+(lane&15), kq)];
    }
    #pragma unroll
    for (int m=0;m<4;m++)
      #pragma unroll
      for (int n2=0;n2<2;n2++){
        au[m][n2]=__builtin_amdgcn_mfma_f32_16x16x32_f16(af[m],fu[n2],au[m][n2],0,0,0);
        ag[m][n2]=__builtin_amdgcn_mfma_f32_16x16x32_f16(af[m],fg[n2],ag[m][n2],0,0,0);
      }
  }

  #pragma unroll
  for (int n2=0;n2<2;n2++){
    const int col = bx*64 + wc*32 + n2*16 + (lane&15);
    const float ubv = ub[(size_t)e*EW_ + col];
    const float gbv = gb[(size_t)e*EW_ + col];
    #pragma unroll
    for (int m=0;m<4;m++){
      #pragma unroll
      for (int j=0;j<4;j++){
        const int s = by*128 + wr*64 + m*16 + (lane>>4)*4 + j;
        float upv = f16q(au[m][n2][j] + ubv);
        float gtv = f16q(ag[m][n2][j] + gbv);
        float wv = 0.f;
        if (s < cnt) wv = rw[(size_t)tok_all[z*BS_+s]*NE_ + e];
        float gc = fminf(gtv, 7.0f);
        float uc = fminf(fmaxf(upv,-7.0f),7.0f);
        float glu = gc * (1.f/(1.f+__expf(-gc*1.702f)));
        act[((size_t)z*BS_+s)*ORIG_ + col] = f2h_bits((uc+1.f)*glu*wv);
      }
    }
  }
}

// -- gathered down GEMM: contrib[zz][slot][h] = act·D^T, 128x128, dbuf -------
__global__ __launch_bounds__(256) void k_down(const u16* __restrict__ act,
                                              const float* __restrict__ dw,
                                              const int* __restrict__ cdcs,
                                              const int* __restrict__ cnt_all,
                                              float* __restrict__ contrib)
{
  const int zz=blockIdx.z, bx=blockIdx.x, by=blockIdx.y;
  const int z = zz>>1, kh = zz&1;
  const int cnt = cnt_all[z];
  if (by*128 >= cnt) return;
  const int e = cdcs[z];
  __shared__ __align__(16) u16 ldsA[2][128*LDSP];
  __shared__ __align__(16) u16 ldsB[2][128*LDSP];
  const int tid=threadIdx.x, lane=tid&63, w=tid>>6;
  const int wr=w>>1, wc=w&1;
  const int ar = tid>>2, ach = tid&3;
  const int kbase = kh*1440;

  const u16* ap0 = act + ((size_t)z*BS_ + by*128 + ar)*ORIG_ + kbase + ach*8;
  const u16* ap1 = ap0 + (size_t)64*ORIG_;
  const float* bp0 = dw + (size_t)(bx*128 + ar)*NEWTOT + (size_t)e*EW_ + kbase + ach*8;
  const float* bp1 = bp0 + (size_t)64*NEWTOT;

  f32x4 acc[4][4];
  #pragma unroll
  for (int i=0;i<4;i++)
    #pragma unroll
    for (int j=0;j<4;j++)
      #pragma unroll
      for (int q=0;q<4;q++) acc[i][j][q]=0.f;

  s16x8 ra0 = *(const s16x8*)ap0;
  s16x8 ra1 = *(const s16x8*)ap1;
  fv4 bR00=*(const fv4*)bp0, bR01=*(const fv4*)(bp0+4);
  fv4 bR10=*(const fv4*)bp1, bR11=*(const fv4*)(bp1+4);
  const int NK = 1440/32;  // 45
  for (int kt=0; kt<NK; kt++){
    u16* A = ldsA[kt&1]; u16* B = ldsB[kt&1];
    *(s16x8*)&A[ldsx(ar,    ach)] = ra0;
    *(s16x8*)&A[ldsx(ar+64, ach)] = ra1;
    *(h8*)&B[ldsx(ar,    ach)] = cvt8(bR00,bR01);
    *(h8*)&B[ldsx(ar+64, ach)] = cvt8(bR10,bR11);
    if (kt+1<NK){
      const int k1 = (kt+1)*32;
      ra0 = *(const s16x8*)(ap0 + k1);
      ra1 = *(const s16x8*)(ap1 + k1);
      bR00=*(const fv4*)(bp0+k1); bR01=*(const fv4*)(bp0+k1+4);
      bR10=*(const fv4*)(bp1+k1); bR11=*(const fv4*)(bp1+k1+4);
    }
    __syncthreads();
    const int kq = lane>>4;
    const u16* Ar = ldsA[kt&1]; const u16* Br = ldsB[kt&1];
    h8 af[4], bfr[4];
    #pragma unroll
    for (int m=0;m<4;m++)    af[m]  = *(const h8*)&Ar[ldsx(wr*64+m*16+(lane&15), kq)];
    #pragma unroll
    for (int n2=0;n2<4;n2++) bfr[n2] = *(const h8*)&Br[ldsx(wc*64+n2*16+(lane&15), kq)];
    #pragma unroll
    for (int m=0;m<4;m++)
      #pragma unroll
      for (int n2=0;n2<4;n2++)
        acc[m][n2]=__builtin_amdgcn_mfma_f32_16x16x32_f16(af[m],bfr[n2],acc[m][n2],0,0,0);
  }

  #pragma unroll
  for (int m=0;m<4;m++){
    #pragma unroll
    for (int j=0;j<4;j++){
      const int slot = by*128 + wr*64 + m*16 + (lane>>4)*4 + j;
      #pragma unroll
      for (int n2=0;n2<4;n2++){
        const int col = bx*128 + wc*64 + n2*16 + (lane&15);
        contrib[((size_t)zz*BS_ + slot)*HID + col] = acc[m][n2][j];
      }
    }
  }
}

// ---- combine: out[n][h] = sum over token n's <=4 lists (both kh planes) ----
__global__ __launch_bounds__(256) void k_combine(const float* __restrict__ contrib,
                                                 const int* __restrict__ inv,
                                                 const int* __restrict__ invcnt,
                                                 float* __restrict__ out)
{
  const int gid = blockIdx.x*256 + threadIdx.x;
  const int base = gid*4;
  const int n = base >> 11;
  const int h = base & 2047;
  fv4 acc = {0.f,0.f,0.f,0.f};
  const int c = invcnt[n];
  for (int j=0;j<c;j++){
    const int code = inv[n*4+j];
    const int z = code>>16;
    const int slot = code & 0xFFFF;
    const float* p = contrib + ((size_t)(z*2)*BS_ + slot)*HID + h;
    acc += *(const fv4*)p;
    acc += *(const fv4*)(p + (size_t)BS_*HID);
  }
  *(fv4*)(out + base) = acc;
}

extern "C" void kernel_launch(void* const* d_in, const int* in_sizes, int n_in,
                              void* d_out, int out_size, void* d_ws, size_t ws_size,
                              hipStream_t stream)
{
  const float* x  = (const float*)d_in[0];
  const float* gw = (const float*)d_in[1];
  const float* u  = (const float*)d_in[2];
  const float* g  = (const float*)d_in[3];
  const float* dw = (const float*)d_in[4];
  const float* ub = (const float*)d_in[5];
  const float* gb = (const float*)d_in[6];

  char* ws = (char*)d_ws;
  size_t off = 0;
  auto alloc = [&](size_t bytes)->void*{ void* p = ws + off; off += (bytes + 255) & ~(size_t)255; return p; };
  float* rw     = (float*)alloc((size_t)BS_*NE_*4);
  float* rwf    = (float*)alloc((size_t)BS_*NE_*4);
  int*   counts = (int*)  alloc(NE_*4);
  int*   invcnt = (int*)  alloc(BS_*4);
  size_t zero_span = off;             // rw+rwf+counts+invcnt must start zeroed
  int*   cdcs   = (int*)  alloc(16*4);
  int*   cnt_all= (int*)  alloc(16*4);
  int*   tok_all= (int*)  alloc((size_t)16*BS_*4);
  int*   inv    = (int*)  alloc((size_t)BS_*4*4);
  u16*   act    = (u16*)  alloc((size_t)16*BS_*ORIG_*2);
  float* contrib= (float*)alloc((size_t)32*BS_*HID*4);
  if (off > ws_size) return;

  hipMemsetAsync(ws, 0, zero_span, stream);

  k_gate <<<BS_/4, 256, 0, stream>>>(x, gw, rw, rwf, counts);
  k_rank <<<1,     64,  0, stream>>>(counts, cdcs);
  k_lists<<<16,    256, 0, stream>>>(rw, rwf, cdcs, tok_all, cnt_all, inv, invcnt);

  k_fused<<<dim3(ORIG_/64, 8, 16), 256, 0, stream>>>(x, u, g, ub, gb, rw,
                                                     cdcs, tok_all, cnt_all, act);
  k_down <<<dim3(HID/128, 8, 32), 256, 0, stream>>>(act, dw, cdcs, cnt_all, contrib);
  k_combine<<<(BS_*HID/4)/256, 256, 0, stream>>>(contrib, inv, invcnt, (float*)d_out);
}

// Round 12
// 574.964 us; speedup vs baseline: 1.7185x; 1.1174x over previous
//
#include <hip/hip_runtime.h>

#define HID 2048
#define NE_ 32
#define EW_ 2944
#define ORIG_ 2880
#define TOPK_ 4
#define MAXNNZ_ 256
#define BS_ 1024
#define NEWTOT (NE_*EW_)
#define LDSP 40   // padded LDS row stride in halves (80B, 16B-aligned rows)

typedef unsigned short u16;
typedef _Float16 h8  __attribute__((ext_vector_type(8)));
typedef float  f32x4 __attribute__((ext_vector_type(4)));
typedef float  fv4   __attribute__((ext_vector_type(4)));

__device__ __forceinline__ u16 f2h_bits(float f){
  union{ _Float16 h; u16 u; } c; c.h = (_Float16)f; return c.u;
}
__device__ __forceinline__ float h2f_bits(u16 u){
  union{ _Float16 h; u16 u; } c; c.u = u; return (float)c.h;
}
__device__ __forceinline__ float f16q(float f){ return (float)(_Float16)f; }

__device__ __forceinline__ h8 cvt8(fv4 a, fv4 b){
  h8 r;
  r[0]=(_Float16)a[0]; r[1]=(_Float16)a[1]; r[2]=(_Float16)a[2]; r[3]=(_Float16)a[3];
  r[4]=(_Float16)b[0]; r[5]=(_Float16)b[1]; r[6]=(_Float16)b[2]; r[7]=(_Float16)b[3];
  return r;
}
__device__ __forceinline__ int ldsx(int row, int q8){ return row*LDSP + q8*8; }

// ---------------- x -> f16 copy (xh is L2-resident, 4 MB) -------------------
__global__ __launch_bounds__(256) void k_xcvt(const float* __restrict__ x,
                                              u16* __restrict__ xh)
{
  const int base = (blockIdx.x*256 + threadIdx.x)*8;
  fv4 a = *(const fv4*)(x+base), b = *(const fv4*)(x+base+4);
  *(h8*)(xh+base) = cvt8(a,b);
}

// ---------------- gating: f32 in, f16-quantized logits, top4 ----------------
__global__ __launch_bounds__(256) void k_gate(const float* __restrict__ x,
                                              const float* __restrict__ gw,
                                              float* __restrict__ rw,
                                              float* __restrict__ rwf,
                                              int* __restrict__ counts)
{
  __shared__ float slog[4][NE_];
  const int tid = threadIdx.x, wid = tid>>6, lane = tid&63;
  const int n = blockIdx.x*4 + wid;
  const float* xr = x + (size_t)n*HID + lane*32;
  float xf[32];
  #pragma unroll
  for (int i=0;i<8;i++){
    fv4 v = *(const fv4*)(xr + i*4);
    #pragma unroll
    for (int j=0;j<4;j++) xf[i*4+j] = v[j];
  }
  for (int e=0;e<NE_;e++){
    const float* gr = gw + (size_t)e*HID + lane*32;
    float p = 0.f;
    #pragma unroll
    for (int i=0;i<8;i++){
      fv4 v = *(const fv4*)(gr + i*4);
      #pragma unroll
      for (int j=0;j<4;j++) p += xf[i*4+j]*v[j];
    }
    #pragma unroll
    for (int s=32;s>0;s>>=1) p += __shfl_xor(p, s);
    if (lane==0) slog[wid][e] = f16q(p);
  }
  if (lane==0){
    float mx=-1e30f;
    for (int e=0;e<NE_;e++) mx = fmaxf(mx, slog[wid][e]);
    float pr[NE_]; float sum=0.f;
    for (int e=0;e<NE_;e++){ float v=__expf(slog[wid][e]-mx); pr[e]=v; sum+=v; }
    for (int e=0;e<NE_;e++) pr[e] = pr[e]/sum;
    int   idx[TOPK_]; float val[TOPK_]; bool used[NE_];
    for (int e=0;e<NE_;e++) used[e]=false;
    float vs=0.f;
    for (int k=0;k<TOPK_;k++){
      float best=-1.f; int bi=0;
      for (int e=0;e<NE_;e++) if(!used[e] && pr[e]>best){best=pr[e];bi=e;}
      used[bi]=true; idx[k]=bi; val[k]=best; vs+=best;
    }
    float* rwr  = rw  + (size_t)n*NE_;
    float* rwfr = rwf + (size_t)n*NE_;
    for (int k=0;k<TOPK_;k++){
      float vraw = val[k]/vs;
      float q = f16q(vraw);
      rwr[idx[k]]  = q;
      rwfr[idx[k]] = vraw;
      if (q!=0.f) atomicAdd(counts+idx[k], 1);
    }
  }
}

// ---------------- rank experts by count (desc), tie -> lower index ----------
__global__ void k_rank(const int* __restrict__ counts, int* __restrict__ cdcs)
{
  if (threadIdx.x==0){
    int cnt[NE_]; bool used[NE_];
    for (int e=0;e<NE_;e++){ cnt[e]=counts[e]; used[e]=false; }
    for (int k=0;k<16;k++){
      int best=-1, bi=0;
      for (int e=0;e<NE_;e++) if(!used[e] && cnt[e]>best){best=cnt[e];bi=e;}
      used[bi]=true; cdcs[k]=bi;
    }
  }
}

// per-expert token lists (trimmed to rw!=0) + inverse map token->(z,slot) ----
__global__ __launch_bounds__(256) void k_lists(const float* __restrict__ rw,
                                               const float* __restrict__ rwf,
                                               const int* __restrict__ cdcs,
                                               int* __restrict__ tok_all,
                                               int* __restrict__ cnt_all,
                                               int* __restrict__ inv,
                                               int* __restrict__ invcnt)
{
  __shared__ float v[BS_];
  __shared__ int scnt;
  const int z = blockIdx.x;
  const int e = cdcs[z];
  const int tid = threadIdx.x;
  for (int i=tid;i<BS_;i+=256) tok_all[z*BS_+i] = 0;
  for (int i=tid;i<BS_;i+=256) v[i] = (z<8) ? rw[(size_t)i*NE_+e] : rwf[(size_t)i*NE_+e];
  if (tid==0) scnt = 0;
  __syncthreads();
  for (int i=tid;i<BS_;i+=256){
    bool take;
    if (z<8){
      take = (v[i]!=0.f);
    } else {
      float vi=v[i]; int r=0;
      for (int m=0;m<BS_;m++){
        float vm=v[m];
        r += (vm>vi) || (vm==vi && m<i);
      }
      take = (r<MAXNNZ_) && (rw[(size_t)i*NE_+e]!=0.f);
    }
    if (take){
      int slot = atomicAdd(&scnt,1);
      tok_all[z*BS_+slot] = i;
      int c = atomicAdd(&invcnt[i],1);
      inv[i*4+c] = (z<<16) | slot;
    }
  }
  __syncthreads();
  if (tid==0) cnt_all[z] = scnt;
}

// --- fused up+gate gathered GEMM: 256 rows x 32 cols x {u,g}, 4 waves -------
// dbuf LDS, one barrier/k-step; A from f16 xh (no cvt), B f32->f16 on stage.
__global__ __launch_bounds__(256) void k_fused(const u16* __restrict__ xh,
                                               const float* __restrict__ uw,
                                               const float* __restrict__ gww,
                                               const float* __restrict__ ub,
                                               const float* __restrict__ gb,
                                               const float* __restrict__ rw,
                                               const int* __restrict__ cdcs,
                                               const int* __restrict__ tok_all,
                                               const int* __restrict__ cnt_all,
                                               u16* __restrict__ act)
{
  const int z=blockIdx.z, bx=blockIdx.x, by=blockIdx.y;
  const int cnt = cnt_all[z];
  if (by*256 >= cnt) return;
  const int e = cdcs[z];
  __shared__ __align__(16) u16 ldsA[2][256*LDSP];
  __shared__ __align__(16) u16 ldsB[2][64*LDSP];   // rows 0-31 = U, 32-63 = G
  const int tid=threadIdx.x, lane=tid&63, w=tid>>6;

  // A staging: rows ar+{0,64,128,192} at chunk ach (h8 each)
  const int ar = tid>>2, ach = tid&3;
  const u16* ap[4];
  #pragma unroll
  for (int r=0;r<4;r++){
    const int tok = tok_all[z*BS_ + by*256 + ar + r*64];
    ap[r] = xh + (size_t)tok*HID + ach*8;
  }
  // B staging: row br (0-31 U, 32-63 G) at chunk ach
  const int br = tid>>2;
  const float* bp = (br<32 ? uw  + ((size_t)e*EW_ + bx*32 + br)*HID
                           : gww + ((size_t)e*EW_ + bx*32 + (br-32))*HID) + ach*8;

  f32x4 au[4][2], ag[4][2];
  #pragma unroll
  for (int i=0;i<4;i++)
    #pragma unroll
    for (int j=0;j<2;j++)
      #pragma unroll
      for (int q=0;q<4;q++){ au[i][j][q]=0.f; ag[i][j][q]=0.f; }

  h8 rA[4];
  #pragma unroll
  for (int r=0;r<4;r++) rA[r] = *(const h8*)ap[r];
  fv4 rB0=*(const fv4*)bp, rB1=*(const fv4*)(bp+4);
  const int NK = HID/32;  // 64
  for (int kt=0; kt<NK; kt++){
    u16* A = ldsA[kt&1]; u16* B = ldsB[kt&1];
    #pragma unroll
    for (int r=0;r<4;r++) *(h8*)&A[ldsx(ar + r*64, ach)] = rA[r];
    *(h8*)&B[ldsx(br, ach)] = cvt8(rB0,rB1);
    if (kt+1<NK){
      const int k1=(kt+1)*32;
      #pragma unroll
      for (int r=0;r<4;r++) rA[r] = *(const h8*)(ap[r]+k1);
      rB0=*(const fv4*)(bp+k1); rB1=*(const fv4*)(bp+k1+4);
    }
    __syncthreads();
    const int kq = lane>>4;
    const u16* Ar = ldsA[kt&1]; const u16* Br = ldsB[kt&1];
    h8 af[4], fu[2], fg[2];
    #pragma unroll
    for (int m=0;m<4;m++) af[m] = *(const h8*)&Ar[ldsx(w*64+m*16+(lane&15), kq)];
    #pragma unroll
    for (int n2=0;n2<2;n2++){
      fu[n2] = *(const h8*)&Br[ldsx(n2*16+(lane&15), kq)];
      fg[n2] = *(const h8*)&Br[ldsx(32+n2*16+(lane&15), kq)];
    }
    #pragma unroll
    for (int m=0;m<4;m++)
      #pragma unroll
      for (int n2=0;n2<2;n2++){
        au[m][n2]=__builtin_amdgcn_mfma_f32_16x16x32_f16(af[m],fu[n2],au[m][n2],0,0,0);
        ag[m][n2]=__builtin_amdgcn_mfma_f32_16x16x32_f16(af[m],fg[n2],ag[m][n2],0,0,0);
      }
  }

  #pragma unroll
  for (int n2=0;n2<2;n2++){
    const int col = bx*32 + n2*16 + (lane&15);
    const float ubv = ub[(size_t)e*EW_ + col];
    const float gbv = gb[(size_t)e*EW_ + col];
    #pragma unroll
    for (int m=0;m<4;m++){
      #pragma unroll
      for (int j=0;j<4;j++){
        const int s = by*256 + w*64 + m*16 + (lane>>4)*4 + j;
        if (s < cnt){
          float upv = f16q(au[m][n2][j] + ubv);
          float gtv = f16q(ag[m][n2][j] + gbv);
          float wv = rw[(size_t)tok_all[z*BS_+s]*NE_ + e];
          float gc = fminf(gtv, 7.0f);
          float uc = fminf(fmaxf(upv,-7.0f),7.0f);
          float glu = gc * (1.f/(1.f+__expf(-gc*1.702f)));
          act[((size_t)z*BS_+s)*ORIG_ + col] = f2h_bits((uc+1.f)*glu*wv);
        }
      }
    }
  }
}

// --- gathered down GEMM: 256 rows x 64 cols, f16 contrib, 4 waves, dbuf -----
__global__ __launch_bounds__(256) void k_down(const u16* __restrict__ act,
                                              const float* __restrict__ dw,
                                              const int* __restrict__ cdcs,
                                              const int* __restrict__ cnt_all,
                                              u16* __restrict__ contrib)
{
  const int zz=blockIdx.z, bx=blockIdx.x, by=blockIdx.y;
  const int z = zz>>1, kh = zz&1;
  const int cnt = cnt_all[z];
  if (by*256 >= cnt) return;
  const int e = cdcs[z];
  __shared__ __align__(16) u16 ldsA[2][256*LDSP];
  __shared__ __align__(16) u16 ldsB[2][64*LDSP];
  const int tid=threadIdx.x, lane=tid&63, w=tid>>6;
  const int ar = tid>>2, ach = tid&3;
  const int kbase = kh*1440;

  const u16* ap[4];
  #pragma unroll
  for (int r=0;r<4;r++)
    ap[r] = act + ((size_t)z*BS_ + by*256 + ar + r*64)*ORIG_ + kbase + ach*8;
  const float* bp = dw + (size_t)(bx*64 + ar)*NEWTOT + (size_t)e*EW_ + kbase + ach*8;

  f32x4 acc[4][4];
  #pragma unroll
  for (int i=0;i<4;i++)
    #pragma unroll
    for (int j=0;j<4;j++)
      #pragma unroll
      for (int q=0;q<4;q++) acc[i][j][q]=0.f;

  h8 rA[4];
  #pragma unroll
  for (int r=0;r<4;r++) rA[r] = *(const h8*)ap[r];
  fv4 rB0=*(const fv4*)bp, rB1=*(const fv4*)(bp+4);
  const int NK = 1440/32;  // 45
  for (int kt=0; kt<NK; kt++){
    u16* A = ldsA[kt&1]; u16* B = ldsB[kt&1];
    #pragma unroll
    for (int r=0;r<4;r++) *(h8*)&A[ldsx(ar + r*64, ach)] = rA[r];
    *(h8*)&B[ldsx(ar, ach)] = cvt8(rB0,rB1);
    if (kt+1<NK){
      const int k1 = (kt+1)*32;
      #pragma unroll
      for (int r=0;r<4;r++) rA[r] = *(const h8*)(ap[r]+k1);
      rB0=*(const fv4*)(bp+k1); rB1=*(const fv4*)(bp+k1+4);
    }
    __syncthreads();
    const int kq = lane>>4;
    const u16* Ar = ldsA[kt&1]; const u16* Br = ldsB[kt&1];
    h8 af[4], bfr[4];
    #pragma unroll
    for (int m=0;m<4;m++)    af[m]  = *(const h8*)&Ar[ldsx(w*64+m*16+(lane&15), kq)];
    #pragma unroll
    for (int n2=0;n2<4;n2++) bfr[n2] = *(const h8*)&Br[ldsx(n2*16+(lane&15), kq)];
    #pragma unroll
    for (int m=0;m<4;m++)
      #pragma unroll
      for (int n2=0;n2<4;n2++)
        acc[m][n2]=__builtin_amdgcn_mfma_f32_16x16x32_f16(af[m],bfr[n2],acc[m][n2],0,0,0);
  }

  #pragma unroll
  for (int m=0;m<4;m++){
    #pragma unroll
    for (int j=0;j<4;j++){
      const int slot = by*256 + w*64 + m*16 + (lane>>4)*4 + j;
      if (slot < cnt){
        #pragma unroll
        for (int n2=0;n2<4;n2++){
          const int col = bx*64 + n2*16 + (lane&15);
          contrib[((size_t)zz*BS_ + slot)*HID + col] = f2h_bits(acc[m][n2][j]);
        }
      }
    }
  }
}

// ---- combine: out[n][h] = sum over token n's <=4 lists (both kh planes) ----
__global__ __launch_bounds__(256) void k_combine(const u16* __restrict__ contrib,
                                                 const int* __restrict__ inv,
                                                 const int* __restrict__ invcnt,
                                                 float* __restrict__ out)
{
  const int gid = blockIdx.x*256 + threadIdx.x;
  const int base = gid*8;
  const int n = base >> 11;
  const int h = base & 2047;
  float acc[8];
  #pragma unroll
  for (int q=0;q<8;q++) acc[q]=0.f;
  const int c = invcnt[n];
  for (int j=0;j<c;j++){
    const int code = inv[n*4+j];
    const int z = code>>16;
    const int slot = code & 0xFFFF;
    const u16* p = contrib + ((size_t)(z*2)*BS_ + slot)*HID + h;
    h8 v0 = *(const h8*)p;
    h8 v1 = *(const h8*)(p + (size_t)BS_*HID);
    #pragma unroll
    for (int q=0;q<8;q++) acc[q] += (float)v0[q] + (float)v1[q];
  }
  fv4 o0, o1;
  #pragma unroll
  for (int q=0;q<4;q++){ o0[q]=acc[q]; o1[q]=acc[4+q]; }
  *(fv4*)(out + base) = o0;
  *(fv4*)(out + base + 4) = o1;
}

extern "C" void kernel_launch(void* const* d_in, const int* in_sizes, int n_in,
                              void* d_out, int out_size, void* d_ws, size_t ws_size,
                              hipStream_t stream)
{
  const float* x  = (const float*)d_in[0];
  const float* gw = (const float*)d_in[1];
  const float* u  = (const float*)d_in[2];
  const float* g  = (const float*)d_in[3];
  const float* dw = (const float*)d_in[4];
  const float* ub = (const float*)d_in[5];
  const float* gb = (const float*)d_in[6];

  char* ws = (char*)d_ws;
  size_t off = 0;
  auto alloc = [&](size_t bytes)->void*{ void* p = ws + off; off += (bytes + 255) & ~(size_t)255; return p; };
  float* rw     = (float*)alloc((size_t)BS_*NE_*4);
  float* rwf    = (float*)alloc((size_t)BS_*NE_*4);
  int*   counts = (int*)  alloc(NE_*4);
  int*   invcnt = (int*)  alloc(BS_*4);
  size_t zero_span = off;             // rw+rwf+counts+invcnt must start zeroed
  int*   cdcs   = (int*)  alloc(16*4);
  int*   cnt_all= (int*)  alloc(16*4);
  int*   tok_all= (int*)  alloc((size_t)16*BS_*4);
  int*   inv    = (int*)  alloc((size_t)BS_*4*4);
  u16*   xh     = (u16*)  alloc((size_t)BS_*HID*2);
  u16*   act    = (u16*)  alloc((size_t)16*BS_*ORIG_*2);
  u16*   contrib= (u16*)  alloc((size_t)32*BS_*HID*2);
  if (off > ws_size) return;

  hipMemsetAsync(ws, 0, zero_span, stream);

  k_xcvt <<<BS_*HID/(256*8), 256, 0, stream>>>(x, xh);
  k_gate <<<BS_/4, 256, 0, stream>>>(x, gw, rw, rwf, counts);
  k_rank <<<1,     64,  0, stream>>>(counts, cdcs);
  k_lists<<<16,    256, 0, stream>>>(rw, rwf, cdcs, tok_all, cnt_all, inv, invcnt);

  k_fused<<<dim3(ORIG_/32, 4, 16), 256, 0, stream>>>(xh, u, g, ub, gb, rw,
                                                     cdcs, tok_all, cnt_all, act);
  k_down <<<dim3(HID/64, 4, 32), 256, 0, stream>>>(act, dw, cdcs, cnt_all, contrib);
  k_combine<<<BS_*HID/(256*8), 256, 0, stream>>>(contrib, inv, invcnt, (float*)d_out);
}